// Round 4
// baseline (459.908 us; speedup 1.0000x reference)
//
#include <hip/hip_runtime.h>

#define T_DIM 16384
#define D_DIM 2048
#define GHD   128
#define W_DIM 4
#define B_DIM 8

typedef _Float16 f16x8 __attribute__((ext_vector_type(8)));
typedef float    f32x4 __attribute__((ext_vector_type(4)));

// workspace layout (bytes)
#define WS_W1F  0                              // [64 kk][8 nf][64 lane][8] f16 = 512 KB
#define WS_W2F  (512*1024)                     // [4 w][128 df][4 kk][64 lane][8] f16 = 2 MiB
#define WS_B2T  (WS_W2F + 2*1024*1024)         // [4][2048] f32 = 32 KB
#define WS_HLIN (WS_B2T + 32*1024)             // [16384][128] f16 = 4 MiB

// ---------------------------------------------------------------------------
// prep: repack w1/w2 into f16 MFMA B-fragment layout, b2 -> [w][d].
// k-map: within a 32-wide k step, lane group g=lane>>4 holds k = 8*g + i.
// A-side uses the same map -> any HW k-permutation cancels.
// ---------------------------------------------------------------------------
__global__ __launch_bounds__(256) void prep_kernel(
    const float* __restrict__ w1, const float* __restrict__ w2,
    const float* __restrict__ b2, _Float16* __restrict__ w1f,
    _Float16* __restrict__ w2f, float* __restrict__ b2t) {
  int t = blockIdx.x * 256 + threadIdx.x;
  int lane = t & 63;
  int g = lane >> 4, c = lane & 15;
  if (t < 32768) {                       // W1F: fid = kk*8+nf
    int fid = t >> 6;
    int kk = fid >> 3, nf = fid & 7;
    f16x8 v;
#pragma unroll
    for (int i = 0; i < 8; ++i) {
      int k = 32 * kk + 8 * g + i;
      v[i] = (_Float16)w1[k * GHD + 16 * nf + c];
    }
    *reinterpret_cast<f16x8*>(w1f + (size_t)t * 8) = v;
  } else if (t < 163840) {               // W2F: fid = ((w*128+df)*4+kk)
    int t2 = t - 32768;
    int fid = t2 >> 6;
    int w = fid >> 9, df = (fid >> 2) & 127, kk = fid & 3;
    f16x8 v;
#pragma unroll
    for (int i = 0; i < 8; ++i) {
      int k = 32 * kk + 8 * g + i;
      int n = (16 * df + c) * 4 + w;
      v[i] = (_Float16)w2[(size_t)k * (D_DIM * W_DIM) + n];
    }
    *reinterpret_cast<f16x8*>(w2f + (size_t)t2 * 8) = v;
  } else if (t < 172032) {               // B2T
    int t3 = t - 163840;
    int w = t3 >> 11, d = t3 & 2047;
    b2t[w * D_DIM + d] = b2[d * 4 + w];
  }
}

// ---------------------------------------------------------------------------
// gemm1: Hlin = silu(gen @ w1) as f16 [T][128].
// v2: 1024 blocks x 16 rows; the 8 nf-fragments split 2-per-wave across the
// 4 waves (acc = 8 VGPR) -> 4096 waves total (4/SIMD). A rows shared by all
// waves in the block -> L1 hits after the first wave.
// ---------------------------------------------------------------------------
__global__ __launch_bounds__(256) void gemm1_kernel(
    const float* __restrict__ gen, const _Float16* __restrict__ w1f,
    _Float16* __restrict__ hlin) {
  int tid = threadIdx.x;
  int lane = tid & 63, wv = tid >> 6;
  int g = lane >> 4, c = lane & 15;
  int nf0 = 2 * wv;
  int row = blockIdx.x * 16 + c;
  const float* arow = gen + (size_t)row * D_DIM;

  f32x4 acc0 = {0.f, 0.f, 0.f, 0.f}, acc1 = {0.f, 0.f, 0.f, 0.f};

  for (int kk = 0; kk < 64; ++kk) {
    float4 a0 = *reinterpret_cast<const float4*>(arow + kk * 32 + 8 * g);
    float4 a1 = *reinterpret_cast<const float4*>(arow + kk * 32 + 8 * g + 4);
    f16x8 af;
    af[0] = (_Float16)a0.x; af[1] = (_Float16)a0.y;
    af[2] = (_Float16)a0.z; af[3] = (_Float16)a0.w;
    af[4] = (_Float16)a1.x; af[5] = (_Float16)a1.y;
    af[6] = (_Float16)a1.z; af[7] = (_Float16)a1.w;
    f16x8 b0 = *reinterpret_cast<const f16x8*>(
        w1f + ((size_t)(kk * 8 + nf0) * 64 + lane) * 8);
    f16x8 b1 = *reinterpret_cast<const f16x8*>(
        w1f + ((size_t)(kk * 8 + nf0 + 1) * 64 + lane) * 8);
    acc0 = __builtin_amdgcn_mfma_f32_16x16x32_f16(af, b0, acc0, 0, 0, 0);
    acc1 = __builtin_amdgcn_mfma_f32_16x16x32_f16(af, b1, acc1, 0, 0, 0);
  }
  // D layout: col = lane&15, row = 4*(lane>>4)+reg  [m89-verified]
  int trow = blockIdx.x * 16 + 4 * g;
#pragma unroll
  for (int r = 0; r < 4; ++r) {
    float v0 = acc0[r];
    hlin[(size_t)(trow + r) * GHD + 16 * nf0 + c] =
        (_Float16)(v0 / (1.f + __expf(-v0)));
    float v1 = acc1[r];
    hlin[(size_t)(trow + r) * GHD + 16 * (nf0 + 1) + c] =
        (_Float16)(v1 / (1.f + __expf(-v1)));
  }
}

// ---------------------------------------------------------------------------
// gemm2 + conv + silu fused.  v3 (occupancy attack):
//  - A-frags reloaded from hlin (L2-hot) per w: no 64-reg resident array
//  - x stage vectorized float4 (was 33 scalar loads/thread)
//  - __launch_bounds__(256,3): force <=170 VGPR -> 3 waves/SIMD
// block = 128 t x 64 d; 4 waves (2x2); wave tile 64 x 32.
// ---------------------------------------------------------------------------
__global__ __launch_bounds__(256, 3) void gemm2_kernel(
    const float* __restrict__ x, const _Float16* __restrict__ hlin,
    const _Float16* __restrict__ w2f, const float* __restrict__ b2t,
    const float* __restrict__ cache, const int* __restrict__ cu_seqlens,
    const int* __restrict__ seq_idx, const int* __restrict__ cache_indices,
    const unsigned char* __restrict__ hi_u8, const int* __restrict__ hi_i32,
    float* __restrict__ out) {
  __shared__ float xs[131 * 68];   // rows t_base-3 .. t_base+127, pad 68
  int tid = threadIdx.x;
  int lane = tid & 63, wv = tid >> 6;
  int wr = wv >> 1, wc = wv & 1;
  int g = lane >> 4, c = lane & 15;
  int t_base = (blockIdx.x >> 5) * 128;
  int d_base = (blockIdx.x & 31) * 64;

  // stage x tile, float4-vectorized: 131 rows x 16 float4
  for (int u = tid; u < 131 * 16; u += 256) {
    int r = u >> 4, c4 = u & 15;
    int gr = t_base - 3 + r;
    gr = max(0, min(T_DIM - 1, gr));
    float4 v = *reinterpret_cast<const float4*>(
        x + (size_t)gr * D_DIM + d_base + c4 * 4);
    *reinterpret_cast<float4*>(&xs[r * 68 + c4 * 4]) = v;
  }

  // per-lane row metadata: pos | ci<<16 | hi<<24
  int meta[16];
#pragma unroll
  for (int m = 0; m < 4; ++m)
#pragma unroll
    for (int r = 0; r < 4; ++r) {
      int t = t_base + 64 * wr + 16 * m + 4 * g + r;
      int s = seq_idx[t];
      int pos = t - cu_seqlens[s];
      int ci = cache_indices[s];
      int hi = (hi_u8[s] != 0) | (hi_i32[s] != 0);
      meta[m * 4 + r] = pos | (ci << 16) | (hi << 24);
    }

  float b2v[4][2];
#pragma unroll
  for (int w = 0; w < 4; ++w)
#pragma unroll
    for (int n = 0; n < 2; ++n)
      b2v[w][n] = b2t[w * D_DIM + d_base + 32 * wc + 16 * n + c];

  // A-row base pointers (per m), frag k = 32kk + 8g + i
  const _Float16* arow[4];
#pragma unroll
  for (int m = 0; m < 4; ++m)
    arow[m] = hlin + (size_t)(t_base + 64 * wr + 16 * m + c) * GHD + 8 * g;

  __syncthreads();

  f32x4 oacc[4][2];
#pragma unroll
  for (int m = 0; m < 4; ++m) {
    oacc[m][0] = f32x4{0.f, 0.f, 0.f, 0.f};
    oacc[m][1] = f32x4{0.f, 0.f, 0.f, 0.f};
  }

  int df0 = (d_base >> 4) + 2 * wc;

#pragma unroll
  for (int w = 0; w < 4; ++w) {
    f32x4 acc[4][2];
#pragma unroll
    for (int m = 0; m < 4; ++m) {
      acc[m][0] = f32x4{0.f, 0.f, 0.f, 0.f};
      acc[m][1] = f32x4{0.f, 0.f, 0.f, 0.f};
    }
#pragma unroll
    for (int kk = 0; kk < 4; ++kk) {
      f16x8 B0 = *reinterpret_cast<const f16x8*>(
          w2f + ((size_t)((w * 128 + df0) * 4 + kk) * 64 + lane) * 8);
      f16x8 B1 = *reinterpret_cast<const f16x8*>(
          w2f + ((size_t)((w * 128 + df0 + 1) * 4 + kk) * 64 + lane) * 8);
      f16x8 A0 = *reinterpret_cast<const f16x8*>(arow[0] + 32 * kk);
      f16x8 A1 = *reinterpret_cast<const f16x8*>(arow[1] + 32 * kk);
      f16x8 A2 = *reinterpret_cast<const f16x8*>(arow[2] + 32 * kk);
      f16x8 A3 = *reinterpret_cast<const f16x8*>(arow[3] + 32 * kk);
      acc[0][0] = __builtin_amdgcn_mfma_f32_16x16x32_f16(A0, B0, acc[0][0], 0, 0, 0);
      acc[0][1] = __builtin_amdgcn_mfma_f32_16x16x32_f16(A0, B1, acc[0][1], 0, 0, 0);
      acc[1][0] = __builtin_amdgcn_mfma_f32_16x16x32_f16(A1, B0, acc[1][0], 0, 0, 0);
      acc[1][1] = __builtin_amdgcn_mfma_f32_16x16x32_f16(A1, B1, acc[1][1], 0, 0, 0);
      acc[2][0] = __builtin_amdgcn_mfma_f32_16x16x32_f16(A2, B0, acc[2][0], 0, 0, 0);
      acc[2][1] = __builtin_amdgcn_mfma_f32_16x16x32_f16(A2, B1, acc[2][1], 0, 0, 0);
      acc[3][0] = __builtin_amdgcn_mfma_f32_16x16x32_f16(A3, B0, acc[3][0], 0, 0, 0);
      acc[3][1] = __builtin_amdgcn_mfma_f32_16x16x32_f16(A3, B1, acc[3][1], 0, 0, 0);
    }
    int o = 3 - w;
#pragma unroll
    for (int m = 0; m < 4; ++m)
#pragma unroll
      for (int r = 0; r < 4; ++r) {
        int mt = meta[m * 4 + r];
        int pos = mt & 0xffff;
        int row_l = 64 * wr + 16 * m + 4 * g + r;
#pragma unroll
        for (int n = 0; n < 2; ++n) {
          int col = 32 * wc + 16 * n + c;
          float ctx;
          if (pos >= o) {
            ctx = xs[(row_l + 3 - o) * 68 + col];
          } else if ((mt >> 24) & 1) {
            int ci = (mt >> 16) & 0xff;
            ctx = cache[(size_t)ci * (D_DIM * W_DIM) +
                        (size_t)(d_base + col) * W_DIM + (4 + pos - o)];
          } else {
            ctx = 0.f;
          }
          oacc[m][n][r] += (acc[m][n][r] + b2v[w][n]) * ctx;
        }
      }
  }

#pragma unroll
  for (int m = 0; m < 4; ++m)
#pragma unroll
    for (int r = 0; r < 4; ++r) {
      int t = t_base + 64 * wr + 16 * m + 4 * g + r;
#pragma unroll
      for (int n = 0; n < 2; ++n) {
        int col = d_base + 32 * wc + 16 * n + c;
        float v = oacc[m][n][r];
        out[(size_t)t * D_DIM + col] = v / (1.f + __expf(-v));
      }
    }
}

// ---------------------------------------------------------------------------
// cache update
// ---------------------------------------------------------------------------
__global__ __launch_bounds__(256) void cache_kernel(
    const float* __restrict__ x, const float* __restrict__ cache,
    const int* __restrict__ cu, const int* __restrict__ ci_arr,
    const unsigned char* __restrict__ hi_u8, const int* __restrict__ hi_i32,
    float* __restrict__ outc) {
  int idx = blockIdx.x * 256 + threadIdx.x;
  if (idx >= B_DIM * D_DIM * W_DIM) return;
  int b = idx >> 13, d = (idx >> 2) & 2047, j = idx & 3;
  float val = cache[idx];
  if (j >= 1) {
    for (int i = 0; i < B_DIM; ++i) {   // last-wins scatter semantics
      if (ci_arr[i] == b) {
        int L = cu[i + 1] - cu[i];
        int rel = L - (W_DIM - 1) + (j - 1);
        if (rel >= 0) {
          int tok = cu[i] + rel;
          tok = max(0, min(T_DIM - 1, tok));
          val = x[(size_t)tok * D_DIM + d];
        } else {
          bool hi = (hi_u8[i] != 0) | (hi_i32[i] != 0);
          int slot = 4 + rel;
          slot = max(0, min(3, slot));
          val = hi ? cache[b * (D_DIM * W_DIM) + d * 4 + slot]
                   : cache[b * (D_DIM * W_DIM) + d * 4 + j];
        }
      }
    }
  }
  outc[idx] = val;
}

extern "C" void kernel_launch(void* const* d_in, const int* in_sizes, int n_in,
                              void* d_out, int out_size, void* d_ws, size_t ws_size,
                              hipStream_t stream) {
  const float* x     = (const float*)d_in[0];
  const float* gen   = (const float*)d_in[1];
  const float* w1    = (const float*)d_in[2];
  const float* w2    = (const float*)d_in[3];
  const float* b2    = (const float*)d_in[4];
  const float* cache = (const float*)d_in[5];
  const int* cu      = (const int*)d_in[6];
  const int* seq     = (const int*)d_in[7];
  const int* cidx    = (const int*)d_in[8];
  const unsigned char* hi8 = (const unsigned char*)d_in[9];
  const int* hi32          = (const int*)d_in[9];
  float* out = (float*)d_out;

  char* ws = (char*)d_ws;
  _Float16* w1f  = (_Float16*)(ws + WS_W1F);
  _Float16* w2f  = (_Float16*)(ws + WS_W2F);
  float*    b2t  = (float*)(ws + WS_B2T);
  _Float16* hlin = (_Float16*)(ws + WS_HLIN);

  prep_kernel<<<dim3(672), dim3(256), 0, stream>>>(w1, w2, b2, w1f, w2f, b2t);
  gemm1_kernel<<<dim3(1024), dim3(256), 0, stream>>>(gen, w1f, hlin);
  gemm2_kernel<<<dim3(4096), dim3(256), 0, stream>>>(
      x, hlin, w2f, b2t, cache, cu, seq, cidx, hi8, hi32, out);
  cache_kernel<<<dim3(256), dim3(256), 0, stream>>>(
      x, cache, cu, cidx, hi8, hi32, out + (size_t)T_DIM * D_DIM);
}

// Round 6
// 250.678 us; speedup vs baseline: 1.8347x; 1.8347x over previous
//
#include <hip/hip_runtime.h>

#define T_DIM 16384
#define D_DIM 2048
#define GHD   128
#define W_DIM 4
#define B_DIM 8

typedef _Float16 f16x8 __attribute__((ext_vector_type(8)));
typedef float    f32x4 __attribute__((ext_vector_type(4)));

// workspace layout (bytes)
#define WS_W1F  0                              // [64 kk][8 nf][64 lane][8] f16 = 512 KB
#define WS_W2F  (512*1024)                     // [4 w][128 df][4 kk][64 lane][8] f16 = 2 MiB
#define WS_B2T  (WS_W2F + 2*1024*1024)         // [4][2048] f32 = 32 KB
#define WS_HLIN (WS_B2T + 32*1024)             // [16384][128] f16 = 4 MiB

// ---------------------------------------------------------------------------
// prep: repack w1/w2 into f16 MFMA B-fragment layout, b2 -> [w][d].
// k-map: within a 32-wide k step, lane group g=lane>>4 holds k = 8*g + i.
// A-side uses the same map -> any HW k-permutation cancels.
// ---------------------------------------------------------------------------
__global__ __launch_bounds__(256) void prep_kernel(
    const float* __restrict__ w1, const float* __restrict__ w2,
    const float* __restrict__ b2, _Float16* __restrict__ w1f,
    _Float16* __restrict__ w2f, float* __restrict__ b2t) {
  int t = blockIdx.x * 256 + threadIdx.x;
  int lane = t & 63;
  int g = lane >> 4, c = lane & 15;
  if (t < 32768) {                       // W1F: fid = kk*8+nf
    int fid = t >> 6;
    int kk = fid >> 3, nf = fid & 7;
    f16x8 v;
#pragma unroll
    for (int i = 0; i < 8; ++i) {
      int k = 32 * kk + 8 * g + i;
      v[i] = (_Float16)w1[k * GHD + 16 * nf + c];
    }
    *reinterpret_cast<f16x8*>(w1f + (size_t)t * 8) = v;
  } else if (t < 163840) {               // W2F: fid = ((w*128+df)*4+kk)
    int t2 = t - 32768;
    int fid = t2 >> 6;
    int w = fid >> 9, df = (fid >> 2) & 127, kk = fid & 3;
    f16x8 v;
#pragma unroll
    for (int i = 0; i < 8; ++i) {
      int k = 32 * kk + 8 * g + i;
      int n = (16 * df + c) * 4 + w;
      v[i] = (_Float16)w2[(size_t)k * (D_DIM * W_DIM) + n];
    }
    *reinterpret_cast<f16x8*>(w2f + (size_t)t2 * 8) = v;
  } else if (t < 172032) {               // B2T
    int t3 = t - 163840;
    int w = t3 >> 11, d = t3 & 2047;
    b2t[w * D_DIM + d] = b2[d * 4 + w];
  }
}

// ---------------------------------------------------------------------------
// gemm1: Hlin = silu(gen @ w1) as f16 [T][128].
// 1024 blocks x 16 rows; 8 nf-fragments split 2-per-wave across 4 waves.
// ---------------------------------------------------------------------------
__global__ __launch_bounds__(256) void gemm1_kernel(
    const float* __restrict__ gen, const _Float16* __restrict__ w1f,
    _Float16* __restrict__ hlin) {
  int tid = threadIdx.x;
  int lane = tid & 63, wv = tid >> 6;
  int g = lane >> 4, c = lane & 15;
  int nf0 = 2 * wv;
  int row = blockIdx.x * 16 + c;
  const float* arow = gen + (size_t)row * D_DIM;

  f32x4 acc0 = {0.f, 0.f, 0.f, 0.f}, acc1 = {0.f, 0.f, 0.f, 0.f};

  for (int kk = 0; kk < 64; ++kk) {
    float4 a0 = *reinterpret_cast<const float4*>(arow + kk * 32 + 8 * g);
    float4 a1 = *reinterpret_cast<const float4*>(arow + kk * 32 + 8 * g + 4);
    f16x8 af;
    af[0] = (_Float16)a0.x; af[1] = (_Float16)a0.y;
    af[2] = (_Float16)a0.z; af[3] = (_Float16)a0.w;
    af[4] = (_Float16)a1.x; af[5] = (_Float16)a1.y;
    af[6] = (_Float16)a1.z; af[7] = (_Float16)a1.w;
    f16x8 b0 = *reinterpret_cast<const f16x8*>(
        w1f + ((size_t)(kk * 8 + nf0) * 64 + lane) * 8);
    f16x8 b1 = *reinterpret_cast<const f16x8*>(
        w1f + ((size_t)(kk * 8 + nf0 + 1) * 64 + lane) * 8);
    acc0 = __builtin_amdgcn_mfma_f32_16x16x32_f16(af, b0, acc0, 0, 0, 0);
    acc1 = __builtin_amdgcn_mfma_f32_16x16x32_f16(af, b1, acc1, 0, 0, 0);
  }
  int trow = blockIdx.x * 16 + 4 * g;
#pragma unroll
  for (int r = 0; r < 4; ++r) {
    float v0 = acc0[r];
    hlin[(size_t)(trow + r) * GHD + 16 * nf0 + c] =
        (_Float16)(v0 / (1.f + __expf(-v0)));
    float v1 = acc1[r];
    hlin[(size_t)(trow + r) * GHD + 16 * (nf0 + 1) + c] =
        (_Float16)(v1 / (1.f + __expf(-v1)));
  }
}

// ---------------------------------------------------------------------------
// gemm2 + conv + silu fused.  v4: structural VGPR reduction.
// block = 64 t x 64 d, 4 waves 2x2, wave tile 32 x 32.
// Resident A[2][4] = 32 VGPR (was 64); no forced launch bounds; no pointer
// arrays. x staged in LDS (float4). B from W2F via L2.
// ---------------------------------------------------------------------------
__global__ __launch_bounds__(256) void gemm2_kernel(
    const float* __restrict__ x, const _Float16* __restrict__ hlin,
    const _Float16* __restrict__ w2f, const float* __restrict__ b2t,
    const float* __restrict__ cache, const int* __restrict__ cu_seqlens,
    const int* __restrict__ seq_idx, const int* __restrict__ cache_indices,
    const unsigned char* __restrict__ hi_u8, const int* __restrict__ hi_i32,
    float* __restrict__ out) {
  __shared__ float xs[67 * 68];   // rows t_base-3 .. t_base+63, pad 68
  int tid = threadIdx.x;
  int lane = tid & 63, wv = tid >> 6;
  int wr = wv >> 1, wc = wv & 1;
  int g = lane >> 4, c = lane & 15;
  int t_base = (blockIdx.x >> 5) * 64;
  int d_base = (blockIdx.x & 31) * 64;

  // stage x tile: 67 rows x 16 float4 (coalesced, ~4.2 loads/thread)
  for (int u = tid; u < 67 * 16; u += 256) {
    int r = u >> 4, c4 = u & 15;
    int gr = t_base - 3 + r;
    gr = max(0, min(T_DIM - 1, gr));
    *reinterpret_cast<float4*>(&xs[r * 68 + c4 * 4]) =
        *reinterpret_cast<const float4*>(x + (size_t)gr * D_DIM + d_base + c4 * 4);
  }

  // per-lane row metadata: pos | ci<<16 | hi<<24   (rows: 2m x 4r)
  int meta[8];
#pragma unroll
  for (int m = 0; m < 2; ++m)
#pragma unroll
    for (int r = 0; r < 4; ++r) {
      int t = t_base + 32 * wr + 16 * m + 4 * g + r;
      int s = seq_idx[t];
      int pos = t - cu_seqlens[s];
      int ci = cache_indices[s];
      int hi = (hi_u8[s] != 0) | (hi_i32[s] != 0);
      meta[m * 4 + r] = pos | (ci << 16) | (hi << 24);
    }

  float b2v[4][2];
#pragma unroll
  for (int w = 0; w < 4; ++w)
#pragma unroll
    for (int n = 0; n < 2; ++n)
      b2v[w][n] = b2t[w * D_DIM + d_base + 32 * wc + 16 * n + c];

  // resident A fragments: A[m][kk], row = t_base+32wr+16m+c, k = 32kk+8g+i
  f16x8 A00 = *reinterpret_cast<const f16x8*>(
      hlin + (size_t)(t_base + 32 * wr + c) * GHD + 8 * g);
  f16x8 A01 = *reinterpret_cast<const f16x8*>(
      hlin + (size_t)(t_base + 32 * wr + c) * GHD + 32 + 8 * g);
  f16x8 A02 = *reinterpret_cast<const f16x8*>(
      hlin + (size_t)(t_base + 32 * wr + c) * GHD + 64 + 8 * g);
  f16x8 A03 = *reinterpret_cast<const f16x8*>(
      hlin + (size_t)(t_base + 32 * wr + c) * GHD + 96 + 8 * g);
  f16x8 A10 = *reinterpret_cast<const f16x8*>(
      hlin + (size_t)(t_base + 32 * wr + 16 + c) * GHD + 8 * g);
  f16x8 A11 = *reinterpret_cast<const f16x8*>(
      hlin + (size_t)(t_base + 32 * wr + 16 + c) * GHD + 32 + 8 * g);
  f16x8 A12 = *reinterpret_cast<const f16x8*>(
      hlin + (size_t)(t_base + 32 * wr + 16 + c) * GHD + 64 + 8 * g);
  f16x8 A13 = *reinterpret_cast<const f16x8*>(
      hlin + (size_t)(t_base + 32 * wr + 16 + c) * GHD + 96 + 8 * g);

  __syncthreads();

  f32x4 oacc[2][2];
#pragma unroll
  for (int m = 0; m < 2; ++m) {
    oacc[m][0] = f32x4{0.f, 0.f, 0.f, 0.f};
    oacc[m][1] = f32x4{0.f, 0.f, 0.f, 0.f};
  }

  int df0 = (d_base >> 4) + 2 * wc;

#pragma unroll
  for (int w = 0; w < 4; ++w) {
    f32x4 acc[2][2];
#pragma unroll
    for (int m = 0; m < 2; ++m) {
      acc[m][0] = f32x4{0.f, 0.f, 0.f, 0.f};
      acc[m][1] = f32x4{0.f, 0.f, 0.f, 0.f};
    }
#pragma unroll
    for (int kk = 0; kk < 4; ++kk) {
      f16x8 B0 = *reinterpret_cast<const f16x8*>(
          w2f + ((size_t)((w * 128 + df0) * 4 + kk) * 64 + lane) * 8);
      f16x8 B1 = *reinterpret_cast<const f16x8*>(
          w2f + ((size_t)((w * 128 + df0 + 1) * 4 + kk) * 64 + lane) * 8);
      f16x8 Am0 = (kk == 0) ? A00 : (kk == 1) ? A01 : (kk == 2) ? A02 : A03;
      f16x8 Am1 = (kk == 0) ? A10 : (kk == 1) ? A11 : (kk == 2) ? A12 : A13;
      acc[0][0] = __builtin_amdgcn_mfma_f32_16x16x32_f16(Am0, B0, acc[0][0], 0, 0, 0);
      acc[0][1] = __builtin_amdgcn_mfma_f32_16x16x32_f16(Am0, B1, acc[0][1], 0, 0, 0);
      acc[1][0] = __builtin_amdgcn_mfma_f32_16x16x32_f16(Am1, B0, acc[1][0], 0, 0, 0);
      acc[1][1] = __builtin_amdgcn_mfma_f32_16x16x32_f16(Am1, B1, acc[1][1], 0, 0, 0);
    }
    int o = 3 - w;
#pragma unroll
    for (int m = 0; m < 2; ++m)
#pragma unroll
      for (int r = 0; r < 4; ++r) {
        int mt = meta[m * 4 + r];
        int pos = mt & 0xffff;
        int row_l = 32 * wr + 16 * m + 4 * g + r;
#pragma unroll
        for (int n = 0; n < 2; ++n) {
          int col = 32 * wc + 16 * n + c;
          float ctx;
          if (pos >= o) {
            ctx = xs[(row_l + 3 - o) * 68 + col];
          } else if ((mt >> 24) & 1) {
            int ci = (mt >> 16) & 0xff;
            ctx = cache[(size_t)ci * (D_DIM * W_DIM) +
                        (size_t)(d_base + col) * W_DIM + (4 + pos - o)];
          } else {
            ctx = 0.f;
          }
          oacc[m][n][r] += (acc[m][n][r] + b2v[w][n]) * ctx;
        }
      }
  }

#pragma unroll
  for (int m = 0; m < 2; ++m)
#pragma unroll
    for (int r = 0; r < 4; ++r) {
      int t = t_base + 32 * wr + 16 * m + 4 * g + r;
#pragma unroll
      for (int n = 0; n < 2; ++n) {
        int col = d_base + 32 * wc + 16 * n + c;
        float v = oacc[m][n][r];
        out[(size_t)t * D_DIM + col] = v / (1.f + __expf(-v));
      }
    }
}

// ---------------------------------------------------------------------------
// cache update
// ---------------------------------------------------------------------------
__global__ __launch_bounds__(256) void cache_kernel(
    const float* __restrict__ x, const float* __restrict__ cache,
    const int* __restrict__ cu, const int* __restrict__ ci_arr,
    const unsigned char* __restrict__ hi_u8, const int* __restrict__ hi_i32,
    float* __restrict__ outc) {
  int idx = blockIdx.x * 256 + threadIdx.x;
  if (idx >= B_DIM * D_DIM * W_DIM) return;
  int b = idx >> 13, d = (idx >> 2) & 2047, j = idx & 3;
  float val = cache[idx];
  if (j >= 1) {
    for (int i = 0; i < B_DIM; ++i) {   // last-wins scatter semantics
      if (ci_arr[i] == b) {
        int L = cu[i + 1] - cu[i];
        int rel = L - (W_DIM - 1) + (j - 1);
        if (rel >= 0) {
          int tok = cu[i] + rel;
          tok = max(0, min(T_DIM - 1, tok));
          val = x[(size_t)tok * D_DIM + d];
        } else {
          bool hi = (hi_u8[i] != 0) | (hi_i32[i] != 0);
          int slot = 4 + rel;
          slot = max(0, min(3, slot));
          val = hi ? cache[b * (D_DIM * W_DIM) + d * 4 + slot]
                   : cache[b * (D_DIM * W_DIM) + d * 4 + j];
        }
      }
    }
  }
  outc[idx] = val;
}

extern "C" void kernel_launch(void* const* d_in, const int* in_sizes, int n_in,
                              void* d_out, int out_size, void* d_ws, size_t ws_size,
                              hipStream_t stream) {
  const float* x     = (const float*)d_in[0];
  const float* gen   = (const float*)d_in[1];
  const float* w1    = (const float*)d_in[2];
  const float* w2    = (const float*)d_in[3];
  const float* b2    = (const float*)d_in[4];
  const float* cache = (const float*)d_in[5];
  const int* cu      = (const int*)d_in[6];
  const int* seq     = (const int*)d_in[7];
  const int* cidx    = (const int*)d_in[8];
  const unsigned char* hi8 = (const unsigned char*)d_in[9];
  const int* hi32          = (const int*)d_in[9];
  float* out = (float*)d_out;

  char* ws = (char*)d_ws;
  _Float16* w1f  = (_Float16*)(ws + WS_W1F);
  _Float16* w2f  = (_Float16*)(ws + WS_W2F);
  float*    b2t  = (float*)(ws + WS_B2T);
  _Float16* hlin = (_Float16*)(ws + WS_HLIN);

  prep_kernel<<<dim3(672), dim3(256), 0, stream>>>(w1, w2, b2, w1f, w2f, b2t);
  gemm1_kernel<<<dim3(1024), dim3(256), 0, stream>>>(gen, w1f, hlin);
  gemm2_kernel<<<dim3(8192), dim3(256), 0, stream>>>(
      x, hlin, w2f, b2t, cache, cu, seq, cidx, hi8, hi32, out);
  cache_kernel<<<dim3(256), dim3(256), 0, stream>>>(
      x, cache, cu, cidx, hi8, hi32, out + (size_t)T_DIM * D_DIM);
}

// Round 7
// 241.604 us; speedup vs baseline: 1.9036x; 1.0376x over previous
//
#include <hip/hip_runtime.h>

#define T_DIM 16384
#define D_DIM 2048
#define GHD   128
#define W_DIM 4
#define B_DIM 8

typedef _Float16 f16x8 __attribute__((ext_vector_type(8)));
typedef float    f32x4 __attribute__((ext_vector_type(4)));

// workspace layout (bytes)
#define WS_W1F  0                              // [64 kk][8 nf][64 lane][8] f16 = 512 KB
#define WS_W2F  (512*1024)                     // [4 w][128 df][4 kk][64 lane][8] f16 = 2 MiB
#define WS_B2T  (WS_W2F + 2*1024*1024)         // [4][2048] f32 = 32 KB
#define WS_HLIN (WS_B2T + 32*1024)             // [16384][128] f16 = 4 MiB

// ---------------------------------------------------------------------------
// prep: repack w1/w2 into f16 MFMA B-fragment layout, b2 -> [w][d].
// k-map: within a 32-wide k step, lane group g=lane>>4 holds k = 8*g + i.
// A-side uses the same map -> any HW k-permutation cancels.
// ---------------------------------------------------------------------------
__global__ __launch_bounds__(256) void prep_kernel(
    const float* __restrict__ w1, const float* __restrict__ w2,
    const float* __restrict__ b2, _Float16* __restrict__ w1f,
    _Float16* __restrict__ w2f, float* __restrict__ b2t) {
  int t = blockIdx.x * 256 + threadIdx.x;
  int lane = t & 63;
  int g = lane >> 4, c = lane & 15;
  if (t < 32768) {                       // W1F: fid = kk*8+nf
    int fid = t >> 6;
    int kk = fid >> 3, nf = fid & 7;
    f16x8 v;
#pragma unroll
    for (int i = 0; i < 8; ++i) {
      int k = 32 * kk + 8 * g + i;
      v[i] = (_Float16)w1[k * GHD + 16 * nf + c];
    }
    *reinterpret_cast<f16x8*>(w1f + (size_t)t * 8) = v;
  } else if (t < 163840) {               // W2F: fid = ((w*128+df)*4+kk)
    int t2 = t - 32768;
    int fid = t2 >> 6;
    int w = fid >> 9, df = (fid >> 2) & 127, kk = fid & 3;
    f16x8 v;
#pragma unroll
    for (int i = 0; i < 8; ++i) {
      int k = 32 * kk + 8 * g + i;
      int n = (16 * df + c) * 4 + w;
      v[i] = (_Float16)w2[(size_t)k * (D_DIM * W_DIM) + n];
    }
    *reinterpret_cast<f16x8*>(w2f + (size_t)t2 * 8) = v;
  } else if (t < 172032) {               // B2T
    int t3 = t - 163840;
    int w = t3 >> 11, d = t3 & 2047;
    b2t[w * D_DIM + d] = b2[d * 4 + w];
  }
}

// ---------------------------------------------------------------------------
// gemm1: Hlin = silu(gen @ w1) as f16 [T][128].
// 1024 blocks x 16 rows; 8 nf-fragments split 2-per-wave across 4 waves.
// ---------------------------------------------------------------------------
__global__ __launch_bounds__(256) void gemm1_kernel(
    const float* __restrict__ gen, const _Float16* __restrict__ w1f,
    _Float16* __restrict__ hlin) {
  int tid = threadIdx.x;
  int lane = tid & 63, wv = tid >> 6;
  int g = lane >> 4, c = lane & 15;
  int nf0 = 2 * wv;
  int row = blockIdx.x * 16 + c;
  const float* arow = gen + (size_t)row * D_DIM;

  f32x4 acc0 = {0.f, 0.f, 0.f, 0.f}, acc1 = {0.f, 0.f, 0.f, 0.f};

  for (int kk = 0; kk < 64; ++kk) {
    float4 a0 = *reinterpret_cast<const float4*>(arow + kk * 32 + 8 * g);
    float4 a1 = *reinterpret_cast<const float4*>(arow + kk * 32 + 8 * g + 4);
    f16x8 af;
    af[0] = (_Float16)a0.x; af[1] = (_Float16)a0.y;
    af[2] = (_Float16)a0.z; af[3] = (_Float16)a0.w;
    af[4] = (_Float16)a1.x; af[5] = (_Float16)a1.y;
    af[6] = (_Float16)a1.z; af[7] = (_Float16)a1.w;
    f16x8 b0 = *reinterpret_cast<const f16x8*>(
        w1f + ((size_t)(kk * 8 + nf0) * 64 + lane) * 8);
    f16x8 b1 = *reinterpret_cast<const f16x8*>(
        w1f + ((size_t)(kk * 8 + nf0 + 1) * 64 + lane) * 8);
    acc0 = __builtin_amdgcn_mfma_f32_16x16x32_f16(af, b0, acc0, 0, 0, 0);
    acc1 = __builtin_amdgcn_mfma_f32_16x16x32_f16(af, b1, acc1, 0, 0, 0);
  }
  int trow = blockIdx.x * 16 + 4 * g;
#pragma unroll
  for (int r = 0; r < 4; ++r) {
    float v0 = acc0[r];
    hlin[(size_t)(trow + r) * GHD + 16 * nf0 + c] =
        (_Float16)(v0 / (1.f + __expf(-v0)));
    float v1 = acc1[r];
    hlin[(size_t)(trow + r) * GHD + 16 * (nf0 + 1) + c] =
        (_Float16)(v1 / (1.f + __expf(-v1)));
  }
}

// ---------------------------------------------------------------------------
// gemm2 + conv + silu fused.  v5: BARRIER-FREE, no LDS.
// block = 64 t x 64 d, 4 waves 2x2, wave tile 32 x 32.
// ctx read directly from x via L1/L2 (4 lines/instr gather) -> no
// __syncthreads at all; waves run fully independent.
// ---------------------------------------------------------------------------
__global__ __launch_bounds__(256) void gemm2_kernel(
    const float* __restrict__ x, const _Float16* __restrict__ hlin,
    const _Float16* __restrict__ w2f, const float* __restrict__ b2t,
    const float* __restrict__ cache, const int* __restrict__ cu_seqlens,
    const int* __restrict__ seq_idx, const int* __restrict__ cache_indices,
    const unsigned char* __restrict__ hi_u8, const int* __restrict__ hi_i32,
    float* __restrict__ out) {
  int tid = threadIdx.x;
  int lane = tid & 63, wv = tid >> 6;
  int wr = wv >> 1, wc = wv & 1;
  int g = lane >> 4, c = lane & 15;
  int t_base = (blockIdx.x >> 5) * 64;
  int d_base = (blockIdx.x & 31) * 64;

  // per-lane row metadata: pos | ci<<16 | hi<<24   (rows: 2m x 4r)
  int meta[8];
#pragma unroll
  for (int m = 0; m < 2; ++m)
#pragma unroll
    for (int r = 0; r < 4; ++r) {
      int t = t_base + 32 * wr + 16 * m + 4 * g + r;
      int s = seq_idx[t];
      int pos = t - cu_seqlens[s];
      int ci = cache_indices[s];
      int hi = (hi_u8[s] != 0) | (hi_i32[s] != 0);
      meta[m * 4 + r] = pos | (ci << 16) | (hi << 24);
    }

  float b2v[4][2];
#pragma unroll
  for (int w = 0; w < 4; ++w)
#pragma unroll
    for (int n = 0; n < 2; ++n)
      b2v[w][n] = b2t[w * D_DIM + d_base + 32 * wc + 16 * n + c];

  // resident A fragments: A[m][kk], row = t_base+32wr+16m+c, k = 32kk+8g+i
  const _Float16* a0p = hlin + (size_t)(t_base + 32 * wr + c) * GHD + 8 * g;
  const _Float16* a1p = hlin + (size_t)(t_base + 32 * wr + 16 + c) * GHD + 8 * g;
  f16x8 A00 = *reinterpret_cast<const f16x8*>(a0p);
  f16x8 A01 = *reinterpret_cast<const f16x8*>(a0p + 32);
  f16x8 A02 = *reinterpret_cast<const f16x8*>(a0p + 64);
  f16x8 A03 = *reinterpret_cast<const f16x8*>(a0p + 96);
  f16x8 A10 = *reinterpret_cast<const f16x8*>(a1p);
  f16x8 A11 = *reinterpret_cast<const f16x8*>(a1p + 32);
  f16x8 A12 = *reinterpret_cast<const f16x8*>(a1p + 64);
  f16x8 A13 = *reinterpret_cast<const f16x8*>(a1p + 96);

  f32x4 oacc[2][2];
#pragma unroll
  for (int m = 0; m < 2; ++m) {
    oacc[m][0] = f32x4{0.f, 0.f, 0.f, 0.f};
    oacc[m][1] = f32x4{0.f, 0.f, 0.f, 0.f};
  }

  int df0 = (d_base >> 4) + 2 * wc;

#pragma unroll
  for (int w = 0; w < 4; ++w) {
    f32x4 acc[2][2];
#pragma unroll
    for (int m = 0; m < 2; ++m) {
      acc[m][0] = f32x4{0.f, 0.f, 0.f, 0.f};
      acc[m][1] = f32x4{0.f, 0.f, 0.f, 0.f};
    }
#pragma unroll
    for (int kk = 0; kk < 4; ++kk) {
      f16x8 B0 = *reinterpret_cast<const f16x8*>(
          w2f + ((size_t)((w * 128 + df0) * 4 + kk) * 64 + lane) * 8);
      f16x8 B1 = *reinterpret_cast<const f16x8*>(
          w2f + ((size_t)((w * 128 + df0 + 1) * 4 + kk) * 64 + lane) * 8);
      f16x8 Am0 = (kk == 0) ? A00 : (kk == 1) ? A01 : (kk == 2) ? A02 : A03;
      f16x8 Am1 = (kk == 0) ? A10 : (kk == 1) ? A11 : (kk == 2) ? A12 : A13;
      acc[0][0] = __builtin_amdgcn_mfma_f32_16x16x32_f16(Am0, B0, acc[0][0], 0, 0, 0);
      acc[0][1] = __builtin_amdgcn_mfma_f32_16x16x32_f16(Am0, B1, acc[0][1], 0, 0, 0);
      acc[1][0] = __builtin_amdgcn_mfma_f32_16x16x32_f16(Am1, B0, acc[1][0], 0, 0, 0);
      acc[1][1] = __builtin_amdgcn_mfma_f32_16x16x32_f16(Am1, B1, acc[1][1], 0, 0, 0);
    }
    int o = 3 - w;
#pragma unroll
    for (int m = 0; m < 2; ++m)
#pragma unroll
      for (int r = 0; r < 4; ++r) {
        int mt = meta[m * 4 + r];
        int pos = mt & 0xffff;
        int t = t_base + 32 * wr + 16 * m + 4 * g + r;
#pragma unroll
        for (int n = 0; n < 2; ++n) {
          int col = 32 * wc + 16 * n + c;
          float ctx;
          if (pos >= o) {
            ctx = x[(size_t)(t - o) * D_DIM + d_base + col];
          } else if ((mt >> 24) & 1) {
            int ci = (mt >> 16) & 0xff;
            ctx = cache[(size_t)ci * (D_DIM * W_DIM) +
                        (size_t)(d_base + col) * W_DIM + (4 + pos - o)];
          } else {
            ctx = 0.f;
          }
          oacc[m][n][r] += (acc[m][n][r] + b2v[w][n]) * ctx;
        }
      }
  }

#pragma unroll
  for (int m = 0; m < 2; ++m)
#pragma unroll
    for (int r = 0; r < 4; ++r) {
      int t = t_base + 32 * wr + 16 * m + 4 * g + r;
#pragma unroll
      for (int n = 0; n < 2; ++n) {
        int col = d_base + 32 * wc + 16 * n + c;
        float v = oacc[m][n][r];
        out[(size_t)t * D_DIM + col] = v / (1.f + __expf(-v));
      }
    }
}

// ---------------------------------------------------------------------------
// cache update
// ---------------------------------------------------------------------------
__global__ __launch_bounds__(256) void cache_kernel(
    const float* __restrict__ x, const float* __restrict__ cache,
    const int* __restrict__ cu, const int* __restrict__ ci_arr,
    const unsigned char* __restrict__ hi_u8, const int* __restrict__ hi_i32,
    float* __restrict__ outc) {
  int idx = blockIdx.x * 256 + threadIdx.x;
  if (idx >= B_DIM * D_DIM * W_DIM) return;
  int b = idx >> 13, d = (idx >> 2) & 2047, j = idx & 3;
  float val = cache[idx];
  if (j >= 1) {
    for (int i = 0; i < B_DIM; ++i) {   // last-wins scatter semantics
      if (ci_arr[i] == b) {
        int L = cu[i + 1] - cu[i];
        int rel = L - (W_DIM - 1) + (j - 1);
        if (rel >= 0) {
          int tok = cu[i] + rel;
          tok = max(0, min(T_DIM - 1, tok));
          val = x[(size_t)tok * D_DIM + d];
        } else {
          bool hi = (hi_u8[i] != 0) | (hi_i32[i] != 0);
          int slot = 4 + rel;
          slot = max(0, min(3, slot));
          val = hi ? cache[b * (D_DIM * W_DIM) + d * 4 + slot]
                   : cache[b * (D_DIM * W_DIM) + d * 4 + j];
        }
      }
    }
  }
  outc[idx] = val;
}

extern "C" void kernel_launch(void* const* d_in, const int* in_sizes, int n_in,
                              void* d_out, int out_size, void* d_ws, size_t ws_size,
                              hipStream_t stream) {
  const float* x     = (const float*)d_in[0];
  const float* gen   = (const float*)d_in[1];
  const float* w1    = (const float*)d_in[2];
  const float* w2    = (const float*)d_in[3];
  const float* b2    = (const float*)d_in[4];
  const float* cache = (const float*)d_in[5];
  const int* cu      = (const int*)d_in[6];
  const int* seq     = (const int*)d_in[7];
  const int* cidx    = (const int*)d_in[8];
  const unsigned char* hi8 = (const unsigned char*)d_in[9];
  const int* hi32          = (const int*)d_in[9];
  float* out = (float*)d_out;

  char* ws = (char*)d_ws;
  _Float16* w1f  = (_Float16*)(ws + WS_W1F);
  _Float16* w2f  = (_Float16*)(ws + WS_W2F);
  float*    b2t  = (float*)(ws + WS_B2T);
  _Float16* hlin = (_Float16*)(ws + WS_HLIN);

  prep_kernel<<<dim3(672), dim3(256), 0, stream>>>(w1, w2, b2, w1f, w2f, b2t);
  gemm1_kernel<<<dim3(1024), dim3(256), 0, stream>>>(gen, w1f, hlin);
  gemm2_kernel<<<dim3(8192), dim3(256), 0, stream>>>(
      x, hlin, w2f, b2t, cache, cu, seq, cidx, hi8, hi32, out);
  cache_kernel<<<dim3(256), dim3(256), 0, stream>>>(
      x, cache, cu, cidx, hi8, hi32, out + (size_t)T_DIM * D_DIM);
}